// Round 16
// baseline (41.184 us; speedup 1.0000x reference)
//
#include <hip/hip_runtime.h>
#include <hip/hip_bf16.h>
#include <math.h>

#define SEQ   2048
#define CDIM  1024
#define HD    64
#define NROW  16384           // B*T
// log2(e)/32  (softmax scale C^-0.5 = 1/32 folded into the exp2 multiplier)
#define CEXP 0.04508422002778112f

typedef float  f32x4  __attribute__((ext_vector_type(4)));
typedef __bf16 bf16x8 __attribute__((ext_vector_type(8)));
typedef int    i32x4  __attribute__((ext_vector_type(4)));

#define AS1 __attribute__((address_space(1)))
#define AS3 __attribute__((address_space(3)))
#define VWC(N) asm volatile("s_waitcnt vmcnt(" #N ")" ::: "memory")
#define SB0()  __builtin_amdgcn_sched_barrier(0)

// RNE-pack two f32 into one dword of 2 bf16
static __device__ __forceinline__ unsigned pk2(float a, float b) {
    unsigned ua = __builtin_bit_cast(unsigned, a);
    unsigned ub = __builtin_bit_cast(unsigned, b);
    ua += 0x7fffu + ((ua >> 16) & 1u);
    ub += 0x7fffu + ((ub >> 16) & 1u);
    return (ua >> 16) | (ub & 0xffff0000u);
}

static __device__ __forceinline__ bf16x8 cvt8(f32x4 lo, f32x4 hi) {
    i32x4 w = { (int)pk2(lo[0], lo[1]), (int)pk2(lo[2], lo[3]),
                (int)pk2(hi[0], hi[1]), (int)pk2(hi[2], hi[3]) };
    return __builtin_bit_cast(bf16x8, w);
}

// ---------------- kernel 0: W fp32 -> bf16 FRAGMENT layout ----------------------
// Wf[f], f = (ks*4 + nt)*64 + lane: 16B frag = W[nt*16+(lane&15)][ks*32+(lane>>4)*8 .. +8]
// -> proj's B-loads become lane-consecutive 1-KB contiguous instructions.
__global__ __launch_bounds__(256) void wconv_kernel(const float* __restrict__ W,
                                                    uint2* __restrict__ Wf) {
    const int f = blockIdx.x * 256 + threadIdx.x;   // 8192 frags
    const int lane = f & 63, nt = (f >> 6) & 3, ks = f >> 8;
    const int head = nt * 16 + (lane & 15);
    const int k0 = ks * 32 + (lane >> 4) * 8;
    const float* src = W + (size_t)head * CDIM + k0;
    float4 a = *(const float4*)src;
    float4 b = *(const float4*)(src + 4);
    Wf[f * 2]     = make_uint2(pk2(a.x, a.y), pk2(a.z, a.w));
    Wf[f * 2 + 1] = make_uint2(pk2(b.x, b.y), pk2(b.z, b.w));
}

// ---------------- kernel 1: K = x @ W_k^T (contiguous-load pipeline) ------------
// 256 blocks x 256 threads (4 waves, 2 blocks/CU). Wave = 16 rows x 64 heads.
// BK=128 (8 steps). x staged wave-privately: each global_load_lds covers 2 rows
// x 512B contiguous (channel-spread), XOR-swizzle via pre-swizzled source.
// B-frags: 16 contiguous asm loads/step from Wf (L2), depth-1 dbuf ring.
// ZERO barriers; counted vmcnt (wait table derived from linear issue order:
// s0 B0 s1 | per step t: w w [B_{t+1}] w w [s_{t+2}]).
template<int T, int I = 0>
struct BPre {
    static __device__ __forceinline__ void run(f32x4 (&BB)[16], unsigned long long wb) {
        constexpr int j2 = I >> 2, nt = I & 3;
        asm volatile("global_load_dwordx4 %0, %1, off offset:%2"
                     : "=&v"(BB[I])
                     : "v"(wb + (unsigned long long)((T * 4 + j2) * 4096)), "n"(nt * 1024)
                     : "memory");
        if constexpr (I + 1 < 16) BPre<T, I + 1>::run(BB, wb);
    }
};

template<int T, class F>
struct Step {
    static __device__ __forceinline__ void run(f32x4 (&Bev)[16], f32x4 (&Bod)[16],
                                               unsigned long long wb, const char* xbF,
                                               int wid, int lm, int lg,
                                               f32x4 (&acc)[4], F& stage) {
        constexpr int bs = T & 1;
        f32x4 (&BC)[16] = bs ? Bod : Bev;
        f32x4 (&BN)[16] = bs ? Bev : Bod;
        const char* ab = xbF + bs * 32768 + (wid * 16 + lm) * 512;
        const int asw = (lm & 7) << 4;

        auto dot = [&](int j) {
            f32x4 alo = *(const f32x4*)(ab + ((j * 128 + lg * 32) ^ asw));
            f32x4 ahi = *(const f32x4*)(ab + ((j * 128 + lg * 32 + 16) ^ asw));
            bf16x8 A = cvt8(alo, ahi);
            #pragma unroll
            for (int nt = 0; nt < 4; ++nt)
                acc[nt] = __builtin_amdgcn_mfma_f32_16x16x32_bf16(
                    A, __builtin_bit_cast(bf16x8, BC[j * 4 + nt]), acc[nt], 0, 0, 0);
        };

        if constexpr (T < 7) { VWC(20); } else { VWC(12); }
        SB0();
        dot(0);
        if constexpr (T < 7) { VWC(16); } else { VWC(8); }
        SB0();
        dot(1);
        if constexpr (T + 1 <= 7) {
            SB0();
            BPre<T + 1>::run(BN, wb);
            SB0();
        }
        if constexpr (T < 7) { VWC(28); } else { VWC(4); }
        SB0();
        dot(2);
        if constexpr (T < 7) { VWC(24); } else { VWC(0); }
        SB0();
        dot(3);
        if constexpr (T + 2 <= 7) {
            SB0();
            stage(T + 2, (T + 2) & 1);
            SB0();
        }
        if constexpr (T + 1 <= 7)
            Step<T + 1, F>::run(Bev, Bod, wb, xbF, wid, lm, lg, acc, stage);
    }
};

__global__ __launch_bounds__(256, 2) void proj_kernel(const float* __restrict__ x,
                                                      const uint2* __restrict__ Wf,
                                                      unsigned short* __restrict__ Ko,
                                                      uint2* __restrict__ KV2) {
    __shared__ __align__(16) char xb[65536];               // 2 x 32 KB x dbuf
    __shared__ __align__(16) unsigned short tb[4][16][64]; // per-wave Ko transpose

    const int tid = threadIdx.x;
    const int wid = tid >> 6, l = tid & 63, lm = l & 15, lg = l >> 4;
    const int bid = blockIdx.x;

    // stage x tile t (BK=128 floats) for THIS WAVE's 16 rows: 8 instrs, each
    // 2 rows x 512B contiguous; source pre-swizzled so reads XOR-swizzle free.
    auto stage = [&](int t, int bs) {
        #pragma unroll
        for (int i = 0; i < 8; ++i) {
            const int r2 = wid * 16 + 2 * i;
            const int rl = r2 + (l >> 5);
            const int colb = ((l & 31) * 16) ^ ((rl & 7) << 4);
            const float* src = x + (size_t)(bid * 64 + rl) * CDIM + t * 128 + (colb >> 2);
            __builtin_amdgcn_global_load_lds((const AS1 void*)src,
                (AS3 void*)(xb + bs * 32768 + r2 * 512), 16, 0, 0);
        }
    };

    const unsigned long long wb =
        (unsigned long long)(const void*)Wf + (unsigned)(l * 16);
    f32x4 Bev[16], Bod[16];
    f32x4 acc[4];
    acc[0] = acc[1] = acc[2] = acc[3] = (f32x4){0.f, 0.f, 0.f, 0.f};

    SB0();
    stage(0, 0);
    SB0();
    BPre<0>::run(Bev, wb);
    SB0();
    stage(1, 1);
    SB0();

    Step<0, decltype(stage)>::run(Bev, Bod, wb, xb, wid, lm, lg, acc, stage);

    // ---- Ko via wave-local LDS transpose (no barrier: own tb[wid] only) -------
    #pragma unroll
    for (int nt = 0; nt < 4; ++nt)
        #pragma unroll
        for (int r = 0; r < 4; ++r)
            tb[wid][lg * 4 + r][nt * 16 + lm] =
                (unsigned short)(pk2(acc[nt][r], 0.f) & 0xffffu);
    const size_t m0r = (size_t)bid * 64 + wid * 16;
    {
        const char* tbase = (const char*)&tb[wid][0][0];
        i32x4 v0 = *(const i32x4*)(tbase + l * 16);          // rows 0..7
        i32x4 v1 = *(const i32x4*)(tbase + 1024 + l * 16);   // rows 8..15
        char* kbase = (char*)(Ko + m0r * HD);
        *(i32x4*)(kbase + l * 16)        = v0;
        *(i32x4*)(kbase + 1024 + l * 16) = v1;
    }
    const size_t g = (size_t)bid * 4 + wid;
    #pragma unroll
    for (int nt = 0; nt < 4; ++nt)
        KV2[(g * 4 + nt) * 64 + l] =
            make_uint2(pk2(acc[nt][0], acc[nt][1]), pk2(acc[nt][2], acc[nt][3]));
}

// ---------------- kernel 2: causal flash attention, 4 q-tiles / block (frozen) --
struct KT { bf16x8 ka0, ka1; uint2 bv[4]; };

static __device__ __forceinline__ KT load_tile(const unsigned short* __restrict__ Kb,
                                               const uint2* __restrict__ KVb,
                                               int kt, int lm, int lg, int l) {
    KT t;
    const unsigned short* ar = Kb + (size_t)(kt * 16 + lm) * HD + lg * 8;
    t.ka0 = *(const bf16x8*)ar;
    t.ka1 = *(const bf16x8*)(ar + 32);
    const uint2* vp = KVb + (size_t)kt * 256 + l;
    #pragma unroll
    for (int nt = 0; nt < 4; ++nt) t.bv[nt] = vp[nt * 64];
    return t;
}

static __device__ __forceinline__ void proc_tile(const KT& t, bf16x8 bq0, bf16x8 bq1,
                                                 bool diag, int lm, int lg,
                                                 float& ls, f32x4 o[4]) {
    f32x4 s4 = (f32x4){0.f, 0.f, 0.f, 0.f};
    s4 = __builtin_amdgcn_mfma_f32_16x16x32_bf16(t.ka0, bq0, s4, 0, 0, 0);
    s4 = __builtin_amdgcn_mfma_f32_16x16x32_bf16(t.ka1, bq1, s4, 0, 0, 0);
    float s0 = s4[0], s1 = s4[1], s2 = s4[2], s3 = s4[3];
    if (diag) {
        const int kb = lg * 4;
        s0 = (kb + 0 > lm) ? -1e30f : s0;
        s1 = (kb + 1 > lm) ? -1e30f : s1;
        s2 = (kb + 2 > lm) ? -1e30f : s2;
        s3 = (kb + 3 > lm) ? -1e30f : s3;
    }
    float p0 = __builtin_amdgcn_exp2f(s0 * CEXP);
    float p1 = __builtin_amdgcn_exp2f(s1 * CEXP);
    float p2 = __builtin_amdgcn_exp2f(s2 * CEXP);
    float p3 = __builtin_amdgcn_exp2f(s3 * CEXP);
    ls += (p0 + p1) + (p2 + p3);
    i32x4 pw = { (int)pk2(p0, p1), (int)pk2(p2, p3), 0, 0 };
    bf16x8 pa = __builtin_bit_cast(bf16x8, pw);
    #pragma unroll
    for (int nt = 0; nt < 4; ++nt) {
        i32x4 vw = { (int)t.bv[nt].x, (int)t.bv[nt].y, 0, 0 };
        bf16x8 bvx = __builtin_bit_cast(bf16x8, vw);
        o[nt] = __builtin_amdgcn_mfma_f32_16x16x32_bf16(pa, bvx, o[nt], 0, 0, 0);
    }
}

__global__ __launch_bounds__(256, 1) void attn_kernel(const unsigned short* __restrict__ K,
                                                      const uint2* __restrict__ KV2,
                                                      float* __restrict__ out) {
    __shared__ float oS[4][4][16][68];   // [slot][wave][row][col]
    __shared__ float lS[4][4][16];
    const int tid = threadIdx.x;
    const int wid = tid >> 6, l = tid & 63, lm = l & 15, lg = l >> 4;
    const int b = blockIdx.x >> 5, j = blockIdx.x & 31;
    const int qts[4] = { 2 * j, 2 * j + 1, 126 - 2 * j, 127 - 2 * j };
    const unsigned short* Kb  = K   + (size_t)b * SEQ * HD;
    const uint2*          KVb = KV2 + (size_t)b * 128 * 256;

    bf16x8 bq0[4], bq1[4];
    #pragma unroll
    for (int s = 0; s < 4; ++s) {
        const unsigned short* qr = Kb + (size_t)(qts[s] * 16 + lm) * HD + lg * 8;
        bq0[s] = *(const bf16x8*)qr;
        bq1[s] = *(const bf16x8*)(qr + 32);
    }

    float ls[4] = { 0.f, 0.f, 0.f, 0.f };
    f32x4 o[4][4];
    #pragma unroll
    for (int s = 0; s < 4; ++s)
        #pragma unroll
        for (int nt = 0; nt < 4; ++nt) o[s][nt] = (f32x4){0.f, 0.f, 0.f, 0.f};

    auto process = [&](const KT& t, int kt) {
        #pragma unroll
        for (int s = 0; s < 4; ++s)
            if (kt <= qts[s])   // wave-uniform branch
                proc_tile(t, bq0[s], bq1[s], kt == qts[s], lm, lg, ls[s], o[s]);
    };

    const int qmax = qts[3];
    KT A = load_tile(Kb, KVb, wid, lm, lg, l);
    int kt = wid;
    while (kt + 4 <= qmax) {
        KT B = load_tile(Kb, KVb, kt + 4, lm, lg, l);
        process(A, kt);
        A = B; kt += 4;
    }
    process(A, kt);

    #pragma unroll
    for (int s = 0; s < 4; ++s) {
        float lsum = ls[s];
        lsum += __shfl_xor(lsum, 16);
        lsum += __shfl_xor(lsum, 32);
        #pragma unroll
        for (int nt = 0; nt < 4; ++nt)
            #pragma unroll
            for (int r = 0; r < 4; ++r)
                oS[s][wid][lg * 4 + r][nt * 16 + lm] = o[s][nt][r];
        if (lg == 0) lS[s][wid][lm] = lsum;
    }
    __syncthreads();

    const int slot = wid;
    const int row  = l >> 2;
    const int cg   = l & 3;
    const int qt   = (slot < 2) ? (2 * j + slot) : (126 - 2 * j + (slot - 2));
    float Lsum = lS[slot][0][row] + lS[slot][1][row] + lS[slot][2][row] + lS[slot][3][row];
    const float inv = 1.f / Lsum;
    float* op = out + ((size_t)b * SEQ + qt * 16 + row) * HD + cg * 16;
    #pragma unroll
    for (int q4 = 0; q4 < 4; ++q4) {
        f32x4 a = (f32x4){0.f, 0.f, 0.f, 0.f};
        #pragma unroll
        for (int w = 0; w < 4; ++w)
            a += *(const f32x4*)&oS[slot][w][row][cg * 16 + q4 * 4];
        *(f32x4*)(op + q4 * 4) = a * inv;
    }
}

extern "C" void kernel_launch(void* const* d_in, const int* in_sizes, int n_in,
                              void* d_out, int out_size, void* d_ws, size_t ws_size,
                              hipStream_t stream) {
    const float* x  = (const float*)d_in[0];   // [8,2048,1024] fp32
    const float* Wk = (const float*)d_in[1];   // [64,1024] fp32
    float* o        = (float*)d_out;           // [8,2048,64] fp32
    unsigned short* Kp = (unsigned short*)d_ws;              // bf16 K [16384][64] (2 MB)
    uint2* KV2 = (uint2*)(Kp + (size_t)NROW * HD);           // PV frags (2 MB)
    uint2* Wf  = KV2 + (size_t)1024 * 256;                   // W frags (128 KB)

    wconv_kernel<<<32, 256, 0, stream>>>(Wk, Wf);
    proj_kernel<<<256, 256, 0, stream>>>(x, Wf, Kp, KV2);
    attn_kernel<<<256, 256, 0, stream>>>(Kp, KV2, o);
}

// Round 17
// 38.790 us; speedup vs baseline: 1.0617x; 1.0617x over previous
//
#include <hip/hip_runtime.h>
#include <hip/hip_bf16.h>
#include <math.h>

#define SEQ   2048
#define CDIM  1024
#define HD    64
#define NROW  16384           // B*T
// log2(e)/32  (softmax scale C^-0.5 = 1/32 folded into the exp2 multiplier)
#define CEXP 0.04508422002778112f

typedef float  f32x4  __attribute__((ext_vector_type(4)));
typedef __bf16 bf16x8 __attribute__((ext_vector_type(8)));
typedef int    i32x4  __attribute__((ext_vector_type(4)));

#define AS1 __attribute__((address_space(1)))
#define AS3 __attribute__((address_space(3)))

// RNE-pack two f32 into one dword of 2 bf16
static __device__ __forceinline__ unsigned pk2(float a, float b) {
    unsigned ua = __builtin_bit_cast(unsigned, a);
    unsigned ub = __builtin_bit_cast(unsigned, b);
    ua += 0x7fffu + ((ua >> 16) & 1u);
    ub += 0x7fffu + ((ub >> 16) & 1u);
    return (ua >> 16) | (ub & 0xffff0000u);
}

static __device__ __forceinline__ bf16x8 cvt8(f32x4 lo, f32x4 hi) {
    i32x4 w = { (int)pk2(lo[0], lo[1]), (int)pk2(lo[2], lo[3]),
                (int)pk2(hi[0], hi[1]), (int)pk2(hi[2], hi[3]) };
    return __builtin_bit_cast(bf16x8, w);
}

// ---------------- kernel 1: K = x @ W_k^T (r15 pipeline + k-rotation) -----------
// 256 blocks x 256 threads (4 waves, 1 block/CU). Wave = 16 rows x 64 heads,
// K-loop = 32 steps of 32. W fp32 -> swizzled bf16 LDS inside this kernel.
// x: 8-deep inline-asm register ring, counted vmcnt, zero main-loop barriers.
// NEW (r17): wave w visits k-steps in rotated order tt=(T+8w)&31 -> the 4
// waves' in-flight load windows cover 4 disjoint 1-KB column ranges, spreading
// the L2/L3 channel interleave (prev: all waves in the same 128-B window).
template<int S>
struct XProl {
    static __device__ __forceinline__ void run(f32x4 (&XA)[8], f32x4 (&XB)[8],
                                               unsigned long long xa, unsigned kb8) {
        const unsigned tt = (S + kb8) & 31u;                 // no wrap for S<8, but cheap
        unsigned long long a = xa + (unsigned long long)(tt * 128u);
        asm volatile("global_load_dwordx4 %0, %2, off\n\t"
                     "global_load_dwordx4 %1, %2, off offset:16"
                     : "=&v"(XA[S]), "=&v"(XB[S])
                     : "v"(a)
                     : "memory");
        if constexpr (S + 1 < 8) XProl<S + 1>::run(XA, XB, xa, kb8);
    }
};

template<int T>
struct XLoop {
    static __device__ __forceinline__ void run(f32x4 (&XA)[8], f32x4 (&XB)[8],
                                               unsigned long long xa, unsigned kb8,
                                               const char* const (&wp)[4][2],
                                               f32x4 (&acc)[4]) {
        constexpr int WT = (T < 24) ? 14 : 2 * (31 - T);
        asm volatile("s_waitcnt vmcnt(%0)" :: "n"(WT) : "memory");
        __builtin_amdgcn_sched_barrier(0);
        const unsigned tt = (T + kb8) & 31u;                 // this visit's k-step
        bf16x8 A = cvt8(XA[T & 7], XB[T & 7]);
        #pragma unroll
        for (int nt = 0; nt < 4; ++nt) {
            // parity (tt&1) == (T&1) since kb8 is even and wrap subtracts 32
            bf16x8 B = *(const bf16x8*)(wp[nt][T & 1] + (tt >> 1) * 128);
            acc[nt] = __builtin_amdgcn_mfma_f32_16x16x32_bf16(A, B, acc[nt], 0, 0, 0);
        }
        if constexpr (T < 24) {
            const unsigned t2 = (T + 8 + kb8) & 31u;
            unsigned long long a = xa + (unsigned long long)(t2 * 128u);
            asm volatile("global_load_dwordx4 %0, %2, off\n\t"
                         "global_load_dwordx4 %1, %2, off offset:16"
                         : "=&v"(XA[T & 7]), "=&v"(XB[T & 7])
                         : "v"(a)
                         : "memory");
        }
        if constexpr (T + 1 < 32) XLoop<T + 1>::run(XA, XB, xa, kb8, wp, acc);
    }
};

__global__ __launch_bounds__(256, 1) void proj_kernel(const float* __restrict__ x,
                                                      const float* __restrict__ W,
                                                      unsigned short* __restrict__ Ko,
                                                      uint2* __restrict__ KV2) {
    __shared__ __align__(16) char wlds[131072];            // W bf16 [64][1024], swizzled
    __shared__ __align__(16) unsigned short tb[4][16][64]; // per-wave Ko transpose (8 KB)

    const int tid = threadIdx.x;
    const int wid = tid >> 6, l = tid & 63, lm = l & 15, lg = l >> 4;
    const int bid = blockIdx.x;

    // ---- W fp32 -> bf16 -> swizzled LDS (ALL 64 rows; 4 chunks of 16) ---------
    #pragma unroll
    for (int c = 0; c < 4; ++c) {
        float4 wv[16];
        #pragma unroll
        for (int j = 0; j < 16; ++j)
            wv[j] = *(const float4*)(W + ((size_t)(c * 16 + j) * 256 + tid) * 4);
        #pragma unroll
        for (int j = 0; j < 16; ++j) {
            const int r = c * 16 + j;
            uint2 p = make_uint2(pk2(wv[j].x, wv[j].y), pk2(wv[j].z, wv[j].w));
            *(uint2*)(wlds + r * 2048 + ((tid * 8) ^ ((r & 7) << 4))) = p;
        }
    }

    // ---- x pipeline prologue: 8 steps in flight (16 dwordx4), rotated order ---
    const int row = bid * 64 + wid * 16 + lm;
    const unsigned kb8 = (unsigned)(wid * 8);
    unsigned long long xa =
        (unsigned long long)(const void*)(x + (size_t)row * CDIM + lg * 8);
    f32x4 XA[8], XB[8];
    XProl<0>::run(XA, XB, xa, kb8);

    asm volatile("s_waitcnt lgkmcnt(0)" ::: "memory");
    __builtin_amdgcn_sched_barrier(0);
    __builtin_amdgcn_s_barrier();
    __builtin_amdgcn_sched_barrier(0);

    // ---- per-lane W B-frag bases: byte(ks) = (ks>>1)*128 + ((ks&1)^hb)*64 + L --
    const int hb = (lm >> 2) & 1;
    const int L  = ((lg ^ (lm & 3)) << 4);
    const char* wp[4][2];
    #pragma unroll
    for (int nt = 0; nt < 4; ++nt) {
        const char* base = wlds + (nt * 16 + lm) * 2048;
        wp[nt][0] = base + hb * 64 + L;            // even ks
        wp[nt][1] = base + (1 - hb) * 64 + L;      // odd ks
    }

    f32x4 acc[4];
    acc[0] = acc[1] = acc[2] = acc[3] = (f32x4){0.f, 0.f, 0.f, 0.f};
    XLoop<0>::run(XA, XB, xa, kb8, wp, acc);

    // ---- Ko via wave-local LDS transpose (no barrier: own tb[wid] only) -------
    #pragma unroll
    for (int nt = 0; nt < 4; ++nt)
        #pragma unroll
        for (int r = 0; r < 4; ++r)
            tb[wid][lg * 4 + r][nt * 16 + lm] =
                (unsigned short)(pk2(acc[nt][r], 0.f) & 0xffffu);
    const size_t m0r = (size_t)bid * 64 + wid * 16;
    {
        const char* tbase = (const char*)&tb[wid][0][0];
        i32x4 v0 = *(const i32x4*)(tbase + l * 16);          // rows 0..7
        i32x4 v1 = *(const i32x4*)(tbase + 1024 + l * 16);   // rows 8..15
        char* kbase = (char*)(Ko + m0r * HD);
        *(i32x4*)(kbase + l * 16)        = v0;
        *(i32x4*)(kbase + 1024 + l * 16) = v1;
    }
    const size_t g = (size_t)bid * 4 + wid;
    #pragma unroll
    for (int nt = 0; nt < 4; ++nt)
        KV2[(g * 4 + nt) * 64 + l] =
            make_uint2(pk2(acc[nt][0], acc[nt][1]), pk2(acc[nt][2], acc[nt][3]));
}

// ---------------- kernel 2: causal flash attention, 4 q-tiles / block (frozen) --
struct KT { bf16x8 ka0, ka1; uint2 bv[4]; };

static __device__ __forceinline__ KT load_tile(const unsigned short* __restrict__ Kb,
                                               const uint2* __restrict__ KVb,
                                               int kt, int lm, int lg, int l) {
    KT t;
    const unsigned short* ar = Kb + (size_t)(kt * 16 + lm) * HD + lg * 8;
    t.ka0 = *(const bf16x8*)ar;
    t.ka1 = *(const bf16x8*)(ar + 32);
    const uint2* vp = KVb + (size_t)kt * 256 + l;
    #pragma unroll
    for (int nt = 0; nt < 4; ++nt) t.bv[nt] = vp[nt * 64];
    return t;
}

static __device__ __forceinline__ void proc_tile(const KT& t, bf16x8 bq0, bf16x8 bq1,
                                                 bool diag, int lm, int lg,
                                                 float& ls, f32x4 o[4]) {
    f32x4 s4 = (f32x4){0.f, 0.f, 0.f, 0.f};
    s4 = __builtin_amdgcn_mfma_f32_16x16x32_bf16(t.ka0, bq0, s4, 0, 0, 0);
    s4 = __builtin_amdgcn_mfma_f32_16x16x32_bf16(t.ka1, bq1, s4, 0, 0, 0);
    float s0 = s4[0], s1 = s4[1], s2 = s4[2], s3 = s4[3];
    if (diag) {
        const int kb = lg * 4;
        s0 = (kb + 0 > lm) ? -1e30f : s0;
        s1 = (kb + 1 > lm) ? -1e30f : s1;
        s2 = (kb + 2 > lm) ? -1e30f : s2;
        s3 = (kb + 3 > lm) ? -1e30f : s3;
    }
    float p0 = __builtin_amdgcn_exp2f(s0 * CEXP);
    float p1 = __builtin_amdgcn_exp2f(s1 * CEXP);
    float p2 = __builtin_amdgcn_exp2f(s2 * CEXP);
    float p3 = __builtin_amdgcn_exp2f(s3 * CEXP);
    ls += (p0 + p1) + (p2 + p3);
    i32x4 pw = { (int)pk2(p0, p1), (int)pk2(p2, p3), 0, 0 };
    bf16x8 pa = __builtin_bit_cast(bf16x8, pw);
    #pragma unroll
    for (int nt = 0; nt < 4; ++nt) {
        i32x4 vw = { (int)t.bv[nt].x, (int)t.bv[nt].y, 0, 0 };
        bf16x8 bvx = __builtin_bit_cast(bf16x8, vw);
        o[nt] = __builtin_amdgcn_mfma_f32_16x16x32_bf16(pa, bvx, o[nt], 0, 0, 0);
    }
}

__global__ __launch_bounds__(256, 1) void attn_kernel(const unsigned short* __restrict__ K,
                                                      const uint2* __restrict__ KV2,
                                                      float* __restrict__ out) {
    __shared__ float oS[4][4][16][68];   // [slot][wave][row][col]
    __shared__ float lS[4][4][16];
    const int tid = threadIdx.x;
    const int wid = tid >> 6, l = tid & 63, lm = l & 15, lg = l >> 4;
    const int b = blockIdx.x >> 5, j = blockIdx.x & 31;
    const int qts[4] = { 2 * j, 2 * j + 1, 126 - 2 * j, 127 - 2 * j };
    const unsigned short* Kb  = K   + (size_t)b * SEQ * HD;
    const uint2*          KVb = KV2 + (size_t)b * 128 * 256;

    bf16x8 bq0[4], bq1[4];
    #pragma unroll
    for (int s = 0; s < 4; ++s) {
        const unsigned short* qr = Kb + (size_t)(qts[s] * 16 + lm) * HD + lg * 8;
        bq0[s] = *(const bf16x8*)qr;
        bq1[s] = *(const bf16x8*)(qr + 32);
    }

    float ls[4] = { 0.f, 0.f, 0.f, 0.f };
    f32x4 o[4][4];
    #pragma unroll
    for (int s = 0; s < 4; ++s)
        #pragma unroll
        for (int nt = 0; nt < 4; ++nt) o[s][nt] = (f32x4){0.f, 0.f, 0.f, 0.f};

    auto process = [&](const KT& t, int kt) {
        #pragma unroll
        for (int s = 0; s < 4; ++s)
            if (kt <= qts[s])   // wave-uniform branch
                proc_tile(t, bq0[s], bq1[s], kt == qts[s], lm, lg, ls[s], o[s]);
    };

    const int qmax = qts[3];
    KT A = load_tile(Kb, KVb, wid, lm, lg, l);
    int kt = wid;
    while (kt + 4 <= qmax) {
        KT B = load_tile(Kb, KVb, kt + 4, lm, lg, l);
        process(A, kt);
        A = B; kt += 4;
    }
    process(A, kt);

    #pragma unroll
    for (int s = 0; s < 4; ++s) {
        float lsum = ls[s];
        lsum += __shfl_xor(lsum, 16);
        lsum += __shfl_xor(lsum, 32);
        #pragma unroll
        for (int nt = 0; nt < 4; ++nt)
            #pragma unroll
            for (int r = 0; r < 4; ++r)
                oS[s][wid][lg * 4 + r][nt * 16 + lm] = o[s][nt][r];
        if (lg == 0) lS[s][wid][lm] = lsum;
    }
    __syncthreads();

    const int slot = wid;
    const int row  = l >> 2;
    const int cg   = l & 3;
    const int qt   = (slot < 2) ? (2 * j + slot) : (126 - 2 * j + (slot - 2));
    float Lsum = lS[slot][0][row] + lS[slot][1][row] + lS[slot][2][row] + lS[slot][3][row];
    const float inv = 1.f / Lsum;
    float* op = out + ((size_t)b * SEQ + qt * 16 + row) * HD + cg * 16;
    #pragma unroll
    for (int q4 = 0; q4 < 4; ++q4) {
        f32x4 a = (f32x4){0.f, 0.f, 0.f, 0.f};
        #pragma unroll
        for (int w = 0; w < 4; ++w)
            a += *(const f32x4*)&oS[slot][w][row][cg * 16 + q4 * 4];
        *(f32x4*)(op + q4 * 4) = a * inv;
    }
}

extern "C" void kernel_launch(void* const* d_in, const int* in_sizes, int n_in,
                              void* d_out, int out_size, void* d_ws, size_t ws_size,
                              hipStream_t stream) {
    const float* x  = (const float*)d_in[0];   // [8,2048,1024] fp32
    const float* Wk = (const float*)d_in[1];   // [64,1024] fp32
    float* o        = (float*)d_out;           // [8,2048,64] fp32
    unsigned short* Kp = (unsigned short*)d_ws;              // bf16 K [16384][64] (2 MB)
    uint2* KV2 = (uint2*)(Kp + (size_t)NROW * HD);           // PV frags (2 MB)

    proj_kernel<<<256, 256, 0, stream>>>(x, Wk, Kp, KV2);
    attn_kernel<<<256, 256, 0, stream>>>(Kp, KV2, o);
}